// Round 3
// baseline (1253.148 us; speedup 1.0000x reference)
//
#include <hip/hip_runtime.h>
#include <hip/hip_bf16.h>

// SimpleRNN fused persistent kernel, round 3.
// T=512, B=1024, IN=128, H=256, OUT=4, K=384. 64 WGs x 16 batch rows, 4 waves.
// Changes vs round 2 (all aimed at the serial per-step latency chain):
//  - logits A-tile replicates W_io rows 4x (row m -> W_io[m&3]) so every lane
//    computes all 4 logits of its batch row l15 -> LOCAL argmax, no shfl.
//  - x never touches LDS: x B-frags built in regs from global dwordx4 loads,
//    3 steps deep -> HBM latency covered; x-side MFMAs (kc 0..3) issue right
//    after the barrier while the 8 h-side ds_read_b128 are in flight.
//  - h buffer XOR-swizzled on 16B chunks (phys = chunk ^ (row&7), 512 B rows):
//    b128 reads and b64 writes are only 2-way bank-aliased (free).
//  - single ldsbar (lgkmcnt only, no vmcnt drain) + ping-pong h buffers.

#define TT    512
#define BBAT  1024
#define INDIM 128
#define HDIM  256
#define KDIM  384
#define NB    16
#define GPAD  264   // gate table row pad (dwords)

typedef __attribute__((ext_vector_type(8))) __bf16 bf16x8;
typedef __attribute__((ext_vector_type(4))) float  fx4;
typedef __attribute__((ext_vector_type(4))) unsigned int ui4;

__device__ __forceinline__ __bf16 f2bf(float f) {
  unsigned u = __builtin_bit_cast(unsigned, f);
  unsigned short r = (unsigned short)((u + 0x7FFFu + ((u >> 16) & 1u)) >> 16);
  return __builtin_bit_cast(__bf16, r);
}

// LDS-only barrier: waits DS ops, does NOT drain vmcnt (global loads/stores
// in flight are wave-private; all cross-wave traffic is LDS).
__device__ __forceinline__ void ldsbar() {
  asm volatile("s_waitcnt lgkmcnt(0)\n\ts_barrier" ::: "memory");
}

__global__ __launch_bounds__(256, 1) void rnn_fused(
    const float* __restrict__ inp,     // [T,B,IN]
    const float* __restrict__ hidden,  // [B,H]
    const float* __restrict__ Wih,     // [H, K]
    const float* __restrict__ bih,     // [H]
    const float* __restrict__ Wio,     // [4, K]
    const float* __restrict__ bio,     // [4]
    const float* __restrict__ act,     // [4, H]
    float* __restrict__ out)           // [T*B*4] ++ [B*H]
{
  // h ping-pong: 16 rows x 256 bf16 (512 B), XOR-swizzled 16B chunks.
  __shared__ __align__(16) __bf16 cb[2][NB * HDIM];
  __shared__ __align__(16) float  gt[4 * GPAD];   // gt[qi][o] = 1 + act[qi][o]

  const int tid  = threadIdx.x;
  const int wave = tid >> 6;
  const int lane = tid & 63;
  const int l15  = lane & 15;   // batch row (B-frag col / D col)
  const int qq   = lane >> 4;
  const int b0   = blockIdx.x * NB;
  const int swz  = l15 & 7;     // XOR swizzle key for this lane's row

  float* outs = out;
  float* hs0  = out + (long)TT * BBAT * 4;

  const float C2 = 2.8853900817779268f;  // 2*log2(e)

  // ---- one-time init ----
#pragma unroll
  for (int qi = 0; qi < 4; ++qi)
    gt[qi * GPAD + tid] = 1.0f + act[qi * HDIM + tid];

  {
    // h0 -> cb[0], swizzled. tid covers 16 rows x 16 float-groups.
    const int row = tid >> 4;
    const int cg  = tid & 15;                  // 16 floats = chunks 2cg, 2cg+1
    const float* hp = hidden + (long)(b0 + row) * HDIM + cg * 16;
    union { ui4 v; __hip_bfloat162 h2[4]; } pk;
#pragma unroll
    for (int half = 0; half < 2; ++half) {
      pk.h2[0] = __float22bfloat162_rn(make_float2(hp[half*8+0], hp[half*8+1]));
      pk.h2[1] = __float22bfloat162_rn(make_float2(hp[half*8+2], hp[half*8+3]));
      pk.h2[2] = __float22bfloat162_rn(make_float2(hp[half*8+4], hp[half*8+5]));
      pk.h2[3] = __float22bfloat162_rn(make_float2(hp[half*8+6], hp[half*8+7]));
      const int chunk = 2 * cg + half;
      *(ui4*)((char*)&cb[0][0] + row * 512 + ((chunk ^ (row & 7)) << 4)) = pk.v;
    }
  }

  // ---- loop-invariant weight A-frags: 4 h-tiles + replicated logits tile ----
  // A[m][k]: h-tiles m = (wave*4+j)*16 + l15 of Wih; logits tile m -> Wio[m&3].
  bf16x8 Wfr[5][12];
#pragma unroll
  for (int j = 0; j < 5; ++j) {
    const float* wbase = (j < 4) ? (Wih + (long)((wave * 4 + j) * 16 + l15) * KDIM)
                                 : (Wio + (long)(l15 & 3) * KDIM);
#pragma unroll
    for (int kc = 0; kc < 12; ++kc) {
      const float* wp = wbase + kc * 32 + qq * 8;
      bf16x8 f;
#pragma unroll
      for (int i = 0; i < 8; ++i) f[i] = f2bf(wp[i]);
      Wfr[j][kc] = f;
    }
  }

  fx4 cbz[4];
#pragma unroll
  for (int j = 0; j < 4; ++j)
    cbz[j] = (*(const fx4*)&bih[(wave * 4 + j) * 16 + qq * 4]) * C2;
  const fx4 bo = *(const fx4*)&bio[0];

  // precomputed LDS byte offsets (swizzled)
  int roff[8], woff[4];
#pragma unroll
  for (int kc = 0; kc < 8; ++kc)
    roff[kc] = l15 * 512 + (((kc * 4 + qq) ^ swz) << 4);
#pragma unroll
  for (int j = 0; j < 4; ++j) {
    const int o0 = (wave * 4 + j) * 16 + qq * 4;
    woff[j] = l15 * 512 + (((o0 >> 3) ^ swz) << 4) + (qq & 1) * 8;
  }

  // ---- x pipeline: regs only, 3 steps deep ----
  fx4 xq[2][8];     // [slot][kc*2+half] f32 staging
  bf16x8 xcur[4];   // current step's x B-frags
  auto loadx = [&](int t, int slot) {
    if (t < TT) {
      const float* xp = inp + ((long)t * BBAT + b0 + l15) * INDIM + qq * 8;
#pragma unroll
      for (int kc = 0; kc < 4; ++kc) {
        xq[slot][kc * 2]     = *(const fx4*)(xp + kc * 32);
        xq[slot][kc * 2 + 1] = *(const fx4*)(xp + kc * 32 + 4);
      }
    }
  };
  auto cvtx = [&](int slot) {
#pragma unroll
    for (int kc = 0; kc < 4; ++kc) {
      union { ui4 v; __hip_bfloat162 h2[4]; } pk;
      const fx4 a = xq[slot][kc * 2], b = xq[slot][kc * 2 + 1];
      pk.h2[0] = __float22bfloat162_rn(make_float2(a[0], a[1]));
      pk.h2[1] = __float22bfloat162_rn(make_float2(a[2], a[3]));
      pk.h2[2] = __float22bfloat162_rn(make_float2(b[0], b[1]));
      pk.h2[3] = __float22bfloat162_rn(make_float2(b[2], b[3]));
      xcur[kc] = __builtin_bit_cast(bf16x8, pk.v);
    }
  };
  loadx(0, 0); cvtx(0);        // x[0] ready now
  loadx(1, 1); loadx(2, 0);    // x[1], x[2] in flight

  __syncthreads();

  // ---- one RNN step ----
  auto stepf = [&](int t, const __bf16* __restrict__ cbR, __bf16* __restrict__ cbW) {
    // h B-frags from LDS (issue first; x-side MFMAs cover the latency)
    bf16x8 hb[8];
#pragma unroll
    for (int kc = 0; kc < 8; ++kc)
      hb[kc] = *(const bf16x8*)((const char*)cbR + roff[kc]);

    fx4 acc[5];
#pragma unroll
    for (int j = 0; j < 5; ++j) { fx4 z = {0.f, 0.f, 0.f, 0.f}; acc[j] = z; }

#pragma unroll
    for (int kc = 0; kc < 4; ++kc)      // x part: B-frags already in regs
#pragma unroll
      for (int j = 0; j < 5; ++j)
        acc[j] = __builtin_amdgcn_mfma_f32_16x16x32_bf16(Wfr[j][kc], xcur[kc], acc[j], 0, 0, 0);
#pragma unroll
    for (int kc = 0; kc < 8; ++kc)      // h part from LDS
#pragma unroll
      for (int j = 0; j < 5; ++j)
        acc[j] = __builtin_amdgcn_mfma_f32_16x16x32_bf16(Wfr[j][kc + 4], hb[kc], acc[j], 0, 0, 0);

    // logits: every lane has all 4 logits of batch row l15 (replicated tile)
    const fx4 lg = acc[4] + bo;
    int qi = 0; float bv = lg[0];
    if (lg[1] > bv) { bv = lg[1]; qi = 1; }
    if (lg[2] > bv) { bv = lg[2]; qi = 2; }
    if (lg[3] > bv) { bv = lg[3]; qi = 3; }
    if (wave == 0 && qq == 0)
      *(fx4*)&outs[((long)t * BBAT + b0 + l15) * 4] = lg;   // 256B coalesced

    // gate rows for this lane's 4 output groups (overlaps the exp chain)
    fx4 g[4];
#pragma unroll
    for (int j = 0; j < 4; ++j)
      g[j] = *(const fx4*)&gt[qi * GPAD + (wave * 4 + j) * 16 + qq * 4];

    // th = tanh(acc+bias) = 1 - 2/(exp2(C2*acc + C2*b) + 1)
#pragma unroll
    for (int j = 0; j < 4; ++j) {
      const fx4 z = acc[j] * C2 + cbz[j];
      fx4 th;
#pragma unroll
      for (int r = 0; r < 4; ++r) {
        const float e  = __builtin_amdgcn_exp2f(z[r]);
        const float rc = __builtin_amdgcn_rcpf(e + 1.0f);
        th[r] = fmaf(-2.0f, rc, 1.0f);
      }
      if (t == 0)
        *(fx4*)&hs0[(long)(b0 + l15) * HDIM + (wave * 4 + j) * 16 + qq * 4] = th;
      const fx4 hg = th * g[j];
      union { unsigned long long u; __hip_bfloat162 h2[2]; } pk;
      pk.h2[0] = __float22bfloat162_rn(make_float2(hg[0], hg[1]));
      pk.h2[1] = __float22bfloat162_rn(make_float2(hg[2], hg[3]));
      *(unsigned long long*)((char*)cbW + woff[j]) = pk.u;
    }

    // advance x pipeline: convert x[t+1], refill slot with x[t+3]
    if (t + 1 < TT) cvtx((t + 1) & 1);
    loadx(t + 3, (t + 1) & 1);

    ldsbar();   // single barrier per step
  };

#pragma unroll 1
  for (int t = 0; t < TT; t += 2) {
    stepf(t,     &cb[0][0], &cb[1][0]);
    stepf(t + 1, &cb[1][0], &cb[0][0]);
  }
}

extern "C" void kernel_launch(void* const* d_in, const int* in_sizes, int n_in,
                              void* d_out, int out_size, void* d_ws, size_t ws_size,
                              hipStream_t stream) {
  const float* inp    = (const float*)d_in[0];
  const float* hidden = (const float*)d_in[1];
  const float* Wih    = (const float*)d_in[2];
  const float* bih    = (const float*)d_in[3];
  const float* Wio    = (const float*)d_in[4];
  const float* bio    = (const float*)d_in[5];
  const float* act    = (const float*)d_in[6];
  float* out = (float*)d_out;
  rnn_fused<<<dim3(BBAT / NB), dim3(256), 0, stream>>>(
      inp, hidden, Wih, bih, Wio, bio, act, out);
}

// Round 4
// 989.080 us; speedup vs baseline: 1.2670x; 1.2670x over previous
//
#include <hip/hip_runtime.h>
#include <hip/hip_bf16.h>

// SimpleRNN fused persistent kernel, round 4.
// T=512, B=1024, IN=128, H=256, OUT=4, K=384. 64 WGs x 16 batch rows, 4 waves.
// R2 structure (cooperative x staging via LDS, 1 barrier/step, ping-pong) plus:
//  - gates resident in VGPRs (16 fx4), cndmask-selected by qi: no LDS gate
//    reads in the loop (they were randomly-banked + latency-chained).
//  - XOR-swizzled h region (16B chunks, phys = c ^ (row&7), 512B rows) and
//    x region (256B rows): b128 reads and b64 writes uniformly bank-spread.
//  - replicated W_io logits tile (row m -> Wio[m&3]): every lane computes all
//    4 logits of its batch row locally -> argmax with zero cross-lane traffic.
//  - x prefetched 2 steps deep (load x[t+2] at step-t top; LDS-write x[t+1]
//    at step-t end): HBM latency fully covered, no vmcnt tail in the chain.

#define TT    512
#define BBAT  1024
#define INDIM 128
#define HDIM  256
#define KDIM  384
#define NB    16
#define HOFF  0      // h region offset in buffer (8192 B: 16 rows x 512 B)
#define XOFF  8192   // x region offset (4096 B: 16 rows x 256 B)
#define BUFSZ 12288

typedef __attribute__((ext_vector_type(8))) __bf16 bf16x8;
typedef __attribute__((ext_vector_type(4))) float  fx4;
typedef __attribute__((ext_vector_type(4))) unsigned int ui4;

__device__ __forceinline__ __bf16 f2bf(float f) {
  unsigned u = __builtin_bit_cast(unsigned, f);
  unsigned short r = (unsigned short)((u + 0x7FFFu + ((u >> 16) & 1u)) >> 16);
  return __builtin_bit_cast(__bf16, r);
}

// LDS-only barrier: waits DS ops, does NOT drain vmcnt (in-flight global
// loads/stores are wave-private; all cross-wave traffic goes through LDS).
__device__ __forceinline__ void ldsbar() {
  asm volatile("s_waitcnt lgkmcnt(0)\n\ts_barrier" ::: "memory");
}

__global__ __launch_bounds__(256, 1) void rnn_fused(
    const float* __restrict__ inp,     // [T,B,IN]
    const float* __restrict__ hidden,  // [B,H]
    const float* __restrict__ Wih,     // [H, K]
    const float* __restrict__ bih,     // [H]
    const float* __restrict__ Wio,     // [4, K]
    const float* __restrict__ bio,     // [4]
    const float* __restrict__ act,     // [4, H]
    float* __restrict__ out)           // [T*B*4] ++ [B*H]
{
  __shared__ __align__(16) char cbuf[2][BUFSZ];   // ping-pong {h | x} bf16

  const int tid  = threadIdx.x;
  const int wave = tid >> 6;
  const int lane = tid & 63;
  const int l15  = lane & 15;   // batch row (B-frag col / D col)
  const int qq   = lane >> 4;
  const int b0   = blockIdx.x * NB;
  const int swz  = l15 & 7;

  float* outs = out;
  float* hs0  = out + (long)TT * BBAT * 4;

  const float C2 = 2.8853900817779268f;  // 2*log2(e)

  // ---- x pipeline: cooperative staging, 2 steps deep ----
  const int xrow = tid >> 4, xcg = tid & 15;
  fx4 xs[2][2];
  auto loadx = [&](int t, int s) {
    if (t < TT) {
      const float* xp = inp + ((long)t * BBAT + b0 + xrow) * INDIM + xcg * 8;
      xs[s][0] = *(const fx4*)xp;
      xs[s][1] = *(const fx4*)(xp + 4);
    }
  };
  const int xwoff = XOFF + xrow * 256 + ((xcg ^ (xrow & 7)) << 4);
  auto writex = [&](int s, char* bufW) {
    union { ui4 v; __hip_bfloat162 h2[4]; } pk;
    pk.h2[0] = __float22bfloat162_rn(make_float2(xs[s][0][0], xs[s][0][1]));
    pk.h2[1] = __float22bfloat162_rn(make_float2(xs[s][0][2], xs[s][0][3]));
    pk.h2[2] = __float22bfloat162_rn(make_float2(xs[s][1][0], xs[s][1][1]));
    pk.h2[3] = __float22bfloat162_rn(make_float2(xs[s][1][2], xs[s][1][3]));
    *(ui4*)(bufW + xwoff) = pk.v;
  };
  loadx(1, 1);   // x[1] in flight across all of init (huge cover)

  // ---- one-time LDS init: h0 and x0 into cbuf[0] (swizzled) ----
  {
    const int row = tid >> 4;
    const int cg  = tid & 15;
    const float* hp = hidden + (long)(b0 + row) * HDIM + cg * 16;
    union { ui4 v; __hip_bfloat162 h2[4]; } pk;
#pragma unroll
    for (int half = 0; half < 2; ++half) {
      pk.h2[0] = __float22bfloat162_rn(make_float2(hp[half*8+0], hp[half*8+1]));
      pk.h2[1] = __float22bfloat162_rn(make_float2(hp[half*8+2], hp[half*8+3]));
      pk.h2[2] = __float22bfloat162_rn(make_float2(hp[half*8+4], hp[half*8+5]));
      pk.h2[3] = __float22bfloat162_rn(make_float2(hp[half*8+6], hp[half*8+7]));
      const int c = 2 * cg + half;
      *(ui4*)(&cbuf[0][0] + HOFF + row * 512 + ((c ^ (row & 7)) << 4)) = pk.v;
    }
    const float* xp = inp + (long)(b0 + row) * INDIM + cg * 8;
    pk.h2[0] = __float22bfloat162_rn(make_float2(xp[0], xp[1]));
    pk.h2[1] = __float22bfloat162_rn(make_float2(xp[2], xp[3]));
    pk.h2[2] = __float22bfloat162_rn(make_float2(xp[4], xp[5]));
    pk.h2[3] = __float22bfloat162_rn(make_float2(xp[6], xp[7]));
    *(ui4*)(&cbuf[0][0] + XOFF + row * 256 + ((cg ^ (row & 7)) << 4)) = pk.v;
  }

  // ---- loop-invariant weight A-frags: 4 h-tiles + replicated logits tile ----
  bf16x8 Wfr[5][12];
#pragma unroll
  for (int j = 0; j < 5; ++j) {
    const float* wbase = (j < 4) ? (Wih + (long)((wave * 4 + j) * 16 + l15) * KDIM)
                                 : (Wio + (long)(l15 & 3) * KDIM);
#pragma unroll
    for (int kc = 0; kc < 12; ++kc) {
      const float* wp = wbase + kc * 32 + qq * 8;
      bf16x8 f;
#pragma unroll
      for (int i = 0; i < 8; ++i) f[i] = f2bf(wp[i]);
      Wfr[j][kc] = f;
    }
  }

  // gates in VGPRs: garr[qi][j] = 1 + act[qi][o0..o0+3]
  fx4 garr[4][4];
#pragma unroll
  for (int qi = 0; qi < 4; ++qi)
#pragma unroll
    for (int j = 0; j < 4; ++j) {
      const fx4 a = *(const fx4*)&act[qi * HDIM + (wave * 4 + j) * 16 + qq * 4];
      garr[qi][j] = a + 1.0f;
    }

  fx4 cbz[4];
#pragma unroll
  for (int j = 0; j < 4; ++j)
    cbz[j] = (*(const fx4*)&bih[(wave * 4 + j) * 16 + qq * 4]) * C2;
  const fx4 bo = *(const fx4*)&bio[0];

  // precomputed swizzled LDS byte offsets
  int roffH[8], roffX[4], woffH[4];
#pragma unroll
  for (int kc = 0; kc < 8; ++kc)
    roffH[kc] = HOFF + l15 * 512 + (((kc * 4 + qq) ^ swz) << 4);
#pragma unroll
  for (int kc = 0; kc < 4; ++kc)
    roffX[kc] = XOFF + l15 * 256 + (((kc * 4 + qq) ^ swz) << 4);
#pragma unroll
  for (int j = 0; j < 4; ++j)
    woffH[j] = HOFF + l15 * 512 +
               (((wave * 8 + j * 2 + (qq >> 1)) ^ swz) << 4) + (qq & 1) * 8;

  __syncthreads();

  // ---- one RNN step ----
  auto stepf = [&](int t, const char* __restrict__ bufR, char* __restrict__ bufW) {
    // 1) all B-frag LDS reads first (head of the chain)
    bf16x8 hb[8], xb[4];
#pragma unroll
    for (int kc = 0; kc < 8; ++kc) hb[kc] = *(const bf16x8*)(bufR + roffH[kc]);
#pragma unroll
    for (int kc = 0; kc < 4; ++kc) xb[kc] = *(const bf16x8*)(bufR + roffX[kc]);

    // 2) prefetch x[t+2] (2 steps of latency cover)
    loadx(t + 2, t & 1);

    fx4 acc[5];
#pragma unroll
    for (int j = 0; j < 5; ++j) { fx4 z = {0.f, 0.f, 0.f, 0.f}; acc[j] = z; }

    // 3) MFMAs; logits acc first in each group so argmax can start early
#pragma unroll
    for (int kc = 0; kc < 4; ++kc) {
      acc[4] = __builtin_amdgcn_mfma_f32_16x16x32_bf16(Wfr[4][kc], xb[kc], acc[4], 0, 0, 0);
      acc[0] = __builtin_amdgcn_mfma_f32_16x16x32_bf16(Wfr[0][kc], xb[kc], acc[0], 0, 0, 0);
      acc[1] = __builtin_amdgcn_mfma_f32_16x16x32_bf16(Wfr[1][kc], xb[kc], acc[1], 0, 0, 0);
      acc[2] = __builtin_amdgcn_mfma_f32_16x16x32_bf16(Wfr[2][kc], xb[kc], acc[2], 0, 0, 0);
      acc[3] = __builtin_amdgcn_mfma_f32_16x16x32_bf16(Wfr[3][kc], xb[kc], acc[3], 0, 0, 0);
    }
#pragma unroll
    for (int kc = 0; kc < 8; ++kc) {
      acc[4] = __builtin_amdgcn_mfma_f32_16x16x32_bf16(Wfr[4][kc + 4], hb[kc], acc[4], 0, 0, 0);
      acc[0] = __builtin_amdgcn_mfma_f32_16x16x32_bf16(Wfr[0][kc + 4], hb[kc], acc[0], 0, 0, 0);
      acc[1] = __builtin_amdgcn_mfma_f32_16x16x32_bf16(Wfr[1][kc + 4], hb[kc], acc[1], 0, 0, 0);
      acc[2] = __builtin_amdgcn_mfma_f32_16x16x32_bf16(Wfr[2][kc + 4], hb[kc], acc[2], 0, 0, 0);
      acc[3] = __builtin_amdgcn_mfma_f32_16x16x32_bf16(Wfr[3][kc + 4], hb[kc], acc[3], 0, 0, 0);
    }

    // 4) logits: every lane has all 4 logits of its batch row (replicated tile)
    const fx4 lg = acc[4] + bo;
    int qi = 0; float bv = lg[0];
    if (lg[1] > bv) { bv = lg[1]; qi = 1; }
    if (lg[2] > bv) { bv = lg[2]; qi = 2; }
    if (lg[3] > bv) { bv = lg[3]; qi = 3; }
    if (wave == 0 && qq == 0)
      *(fx4*)&outs[((long)t * BBAT + b0 + l15) * 4] = lg;   // 256B coalesced

    // 5) gate select from VGPR-resident table (no LDS, overlaps exp chain)
    const bool s0 = (qi & 1) != 0, s1 = (qi & 2) != 0;
    fx4 g[4];
#pragma unroll
    for (int j = 0; j < 4; ++j) {
      const fx4 ga = s0 ? garr[1][j] : garr[0][j];
      const fx4 gb = s0 ? garr[3][j] : garr[2][j];
      g[j] = s1 ? gb : ga;
    }

    // 6) epilogue: th = tanh(acc+bias) = 1 - 2/(exp2(C2*acc + C2*b) + 1)
#pragma unroll
    for (int j = 0; j < 4; ++j) {
      const fx4 z = acc[j] * C2 + cbz[j];
      fx4 th;
#pragma unroll
      for (int r = 0; r < 4; ++r) {
        const float e  = __builtin_amdgcn_exp2f(z[r]);
        const float rc = __builtin_amdgcn_rcpf(e + 1.0f);
        th[r] = fmaf(-2.0f, rc, 1.0f);
      }
      if (t == 0)
        *(fx4*)&hs0[(long)(b0 + l15) * HDIM + (wave * 4 + j) * 16 + qq * 4] = th;
      const fx4 hg = th * g[j];
      union { unsigned long long u; __hip_bfloat162 h2[2]; } pk;
      pk.h2[0] = __float22bfloat162_rn(make_float2(hg[0], hg[1]));
      pk.h2[1] = __float22bfloat162_rn(make_float2(hg[2], hg[3]));
      *(unsigned long long*)(bufW + woffH[j]) = pk.u;
    }

    // 7) stage x[t+1] (loaded at step t-1) into next buffer
    if (t + 1 < TT) writex((t + 1) & 1, bufW);

    ldsbar();   // single barrier per step
  };

#pragma unroll 1
  for (int t = 0; t < TT; t += 2) {
    stepf(t,     &cbuf[0][0], &cbuf[1][0]);
    stepf(t + 1, &cbuf[1][0], &cbuf[0][0]);
  }
}

extern "C" void kernel_launch(void* const* d_in, const int* in_sizes, int n_in,
                              void* d_out, int out_size, void* d_ws, size_t ws_size,
                              hipStream_t stream) {
  const float* inp    = (const float*)d_in[0];
  const float* hidden = (const float*)d_in[1];
  const float* Wih    = (const float*)d_in[2];
  const float* bih    = (const float*)d_in[3];
  const float* Wio    = (const float*)d_in[4];
  const float* bio    = (const float*)d_in[5];
  const float* act    = (const float*)d_in[6];
  float* out = (float*)d_out;
  rnn_fused<<<dim3(BBAT / NB), dim3(256), 0, stream>>>(
      inp, hidden, Wih, bih, Wio, bio, act, out);
}